// Round 7
// baseline (248.561 us; speedup 1.0000x reference)
//
#include <hip/hip_runtime.h>
#include <hip/hip_bf16.h>
#include <math.h>

#define LQ_  2048
#define LK_  2048
#define D_   128
#define LN_EPS 1e-5f
#define TK_  32
#define NTILE (LK_ / TK_)

typedef __attribute__((ext_vector_type(8))) short short8;
typedef __attribute__((ext_vector_type(4))) float f32x4;

union FragU { uint4 u4; short8 s8; unsigned int u[4]; };

__device__ __forceinline__ unsigned int pk_bf16(float a, float b) {
  __hip_bfloat162 h = __float22bfloat162_rn(make_float2(a, b));
  unsigned int u;
  __builtin_memcpy(&u, &h, 4);
  return u;
}
__device__ __forceinline__ float bf_lo(unsigned int u){ unsigned int v = u << 16; float f; __builtin_memcpy(&f, &v, 4); return f; }
__device__ __forceinline__ float bf_hi(unsigned int u){ unsigned int v = u & 0xffff0000u; float f; __builtin_memcpy(&f, &v, 4); return f; }
__device__ __forceinline__ unsigned short bf16_bits(float x) {
  return (unsigned short)(pk_bf16(x, 0.f) & 0xffffu);
}
// Truncation hi/lo split of two floats -> (hi bf16x2, lo bf16x2).
// hi = bit-truncate (2 VALU for the pair), lo = x - hi exact then rn;
// 3-term MFMA error identical to rn-split (~2^-16 relative).
__device__ __forceinline__ uint2 split_hilo(float a, float b) {
  unsigned int au = __float_as_uint(a), bu = __float_as_uint(b);
  unsigned int hi = (bu & 0xffff0000u) | (au >> 16);
  float la = a - bf_lo(hi);
  float lb = b - bf_hi(hi);
  return make_uint2(hi, pk_bf16(la, lb));
}

// Vt: uint [128 d][20] (16 kp used). chunk = (kp>>2) ^ (d>>5): the XOR term
// carries d bits 5..6 (= writer-lane vc bits 3..4), separating all write
// aliases -> b64 writes land 4/bank (the wave-b64 floor). Reads ~2-way.
__device__ __forceinline__ int idxVt(int d, int kp) {
  return d * 20 + ((((kp >> 2) ^ (d >> 5)) & 3) << 2) + (kp & 3);
}
// Ps: ushort [64 rows][32 cols], 8-ushort-chunk swizzle (verified ~2-way).
__device__ __forceinline__ int idxPs(int row, int col) {
  return row * 32 + ((((col >> 3) ^ (row >> 2)) & 3) << 3) + (col & 7);
}

// LDS-only barrier: drains ds ops, leaves global (vmcnt) loads in flight.
__device__ __forceinline__ void barrier_lds() {
  asm volatile("s_waitcnt lgkmcnt(0)\n\ts_barrier" ::: "memory");
}

__global__ __launch_bounds__(256, 2) void attn_ln_mfma(
    const float* __restrict__ qg, const float* __restrict__ kg,
    const float* __restrict__ vg, const float* __restrict__ maskg,
    const float* __restrict__ gammag, const float* __restrict__ betag,
    float* __restrict__ outg)
{
  __shared__ unsigned int   VtW[2][128 * 20];  // 20 KB (bf16 kv-pairs, dbuf)
  __shared__ unsigned short PsS[2][64 * 32];   // 8 KB  (dbuf)
  __shared__ float          lExch[2 * 64];
  __shared__ float          sExch[2 * 64 * 2];

  const int tid  = threadIdx.x;
  const int w    = tid >> 6;
  const int lane = tid & 63;
  const int quad = lane >> 4;
  const int lr   = lane & 15;
  const int rowgrp = w & 1;     // q-rows rowgrp*32 .. +32
  const int khalf  = w >> 1;    // QK: k-cols khalf*16..+16; PV: d-cols khalf*64..+64

  // XCD swizzle: blocks on XCD x serve batches {2x,2x+1} -> K/V L2-resident.
  const int id   = blockIdx.x;
  const int xcd  = id & 7;
  const int slot = id >> 3;
  const int b    = xcd * 2 + (slot >> 5);
  const int q0   = (slot & 31) * 64;

  // V staging map: thread = (vc: d-chunk 0..31, kp2: pair-of-kv-pairs 0..7)
  const int vc = tid & 31, kp2 = tid >> 5;

  const float* gk = kg + (size_t)b * LK_ * D_;
  const float* gv = vg + (size_t)b * LK_ * D_;

  // Per-lane K B-fragment source: row khalf*16+lr, d = c*32 + quad*8 (+0..7)
  const float* kf = gk + (size_t)(khalf * 16 + lr) * D_ + quad * 8;
  // V staging source: rows 4*kp2..+3, cols vc*4..+3
  const float* vf = gv + (size_t)(4 * kp2) * D_ + vc * 4;

  // ---- prefetch tile 0 ----
  float4 kpre[8];
#pragma unroll
  for (int c = 0; c < 4; c++) {
    kpre[2 * c]     = *(const float4*)(kf + c * 32);
    kpre[2 * c + 1] = *(const float4*)(kf + c * 32 + 4);
  }
  float4 vpre[4];
#pragma unroll
  for (int r = 0; r < 4; r++)
    vpre[r] = *(const float4*)(vf + (size_t)r * D_);

  // ---- Q fragments (hi/lo), registers for the whole loop ----
  short8 qh[2][4], ql[2][4];
#pragma unroll
  for (int rt = 0; rt < 2; rt++) {
    const float* qrow = qg + ((size_t)b * LQ_ + q0 + rowgrp * 32 + rt * 16 + lr) * D_ + quad * 8;
#pragma unroll
    for (int c = 0; c < 4; c++) {
      float4 x = *(const float4*)(qrow + c * 32);
      float4 y = *(const float4*)(qrow + c * 32 + 4);
      uint2 p0 = split_hilo(x.x, x.y);
      uint2 p1 = split_hilo(x.z, x.w);
      uint2 p2 = split_hilo(y.x, y.y);
      uint2 p3 = split_hilo(y.z, y.w);
      FragU H, L;
      H.u[0] = p0.x; H.u[1] = p1.x; H.u[2] = p2.x; H.u[3] = p3.x;
      L.u[0] = p0.y; L.u[1] = p1.y; L.u[2] = p2.y; L.u[3] = p3.y;
      qh[rt][c] = H.s8; ql[rt][c] = L.s8;
    }
  }

  float l_part[2][4];
  f32x4 o[2][4];                 // [rt][nb]: d = khalf*64 + nb*16 + lr
  const f32x4 zf = {0.f, 0.f, 0.f, 0.f};
#pragma unroll
  for (int rt = 0; rt < 2; rt++) {
#pragma unroll
    for (int r = 0; r < 4; r++) l_part[rt][r] = 0.f;
#pragma unroll
    for (int n = 0; n < 4; n++) o[rt][n] = zf;
  }

  for (int kt = 0; kt < NTILE; kt++) {
    const int k0  = kt * TK_;
    const int buf = kt & 1;

    // ---- mask loads (this wave's 32 rows x 16 cols) ----
    float mkv[2][4];
#pragma unroll
    for (int rt = 0; rt < 2; rt++)
#pragma unroll
      for (int reg = 0; reg < 4; reg++)
        mkv[rt][reg] = maskg[(size_t)(q0 + rowgrp * 32 + rt * 16 + quad * 4 + reg) * LK_
                             + k0 + khalf * 16 + lr];

    // ---- S = Q K^T via MFMA; K frags straight from registers (no LDS) ----
    f32x4 sacc[2];
    sacc[0] = zf; sacc[1] = zf;
#pragma unroll
    for (int c = 0; c < 4; c++) {
      FragU kh, kl;
      {
        float4 x = kpre[2 * c], y = kpre[2 * c + 1];
        uint2 p0 = split_hilo(x.x, x.y);
        uint2 p1 = split_hilo(x.z, x.w);
        uint2 p2 = split_hilo(y.x, y.y);
        uint2 p3 = split_hilo(y.z, y.w);
        kh.u[0] = p0.x; kh.u[1] = p1.x; kh.u[2] = p2.x; kh.u[3] = p3.x;
        kl.u[0] = p0.y; kl.u[1] = p1.y; kl.u[2] = p2.y; kl.u[3] = p3.y;
      }
#pragma unroll
      for (int rt = 0; rt < 2; rt++) {
        sacc[rt] = __builtin_amdgcn_mfma_f32_16x16x32_bf16(qh[rt][c], kh.s8, sacc[rt], 0, 0, 0);
        sacc[rt] = __builtin_amdgcn_mfma_f32_16x16x32_bf16(ql[rt][c], kh.s8, sacc[rt], 0, 0, 0);
        sacc[rt] = __builtin_amdgcn_mfma_f32_16x16x32_bf16(qh[rt][c], kl.s8, sacc[rt], 0, 0, 0);
      }
    }

    // ---- prefetch NEXT tile K (in flight across barrier) ----
    if (kt + 1 < NTILE) {
      const float* p = kf + (size_t)(k0 + TK_) * D_;
#pragma unroll
      for (int c = 0; c < 4; c++) {
        kpre[2 * c]     = *(const float4*)(p + c * 32);
        kpre[2 * c + 1] = *(const float4*)(p + c * 32 + 4);
      }
    }

    // ---- max-free softmax; P -> Ps[buf] as bf16 ----
#pragma unroll
    for (int rt = 0; rt < 2; rt++)
#pragma unroll
      for (int reg = 0; reg < 4; reg++) {
        float p = __expf(sacc[rt][reg] + mkv[rt][reg]);
        l_part[rt][reg] += p;
        PsS[buf][idxPs(rowgrp * 32 + rt * 16 + quad * 4 + reg, khalf * 16 + lr)] = bf16_bits(p);
      }

    // ---- stage V^T -> Vt[buf] as bf16 kv-pairs, b64 writes ----
#pragma unroll
    for (int e = 0; e < 4; e++) {
      const float* vx0 = &vpre[0].x, *vx1 = &vpre[1].x, *vx2 = &vpre[2].x, *vx3 = &vpre[3].x;
      uint2 wv = make_uint2(pk_bf16(vx0[e], vx1[e]), pk_bf16(vx2[e], vx3[e]));
      *(uint2*)&VtW[buf][idxVt(vc * 4 + e, 2 * kp2)] = wv;
    }

    // ---- prefetch NEXT tile V ----
    if (kt + 1 < NTILE) {
      const float* p = vf + (size_t)(k0 + TK_) * D_;
#pragma unroll
      for (int r = 0; r < 4; r++)
        vpre[r] = *(const float4*)(p + (size_t)r * D_);
    }

    barrier_lds();   // Ps[buf] + Vt[buf] visible to all waves

    // ---- O += P * V via MFMA; this wave: 32 rows x 64 d-cols, full 32 k ----
    FragU Bv[4];
#pragma unroll
    for (int nb = 0; nb < 4; nb++)
      Bv[nb].u4 = *(const uint4*)&VtW[buf][idxVt(khalf * 64 + nb * 16 + lr, quad * 4)];
#pragma unroll
    for (int rt = 0; rt < 2; rt++) {
      FragU A;
      A.u4 = *(const uint4*)&PsS[buf][idxPs(rowgrp * 32 + rt * 16 + lr, quad * 8)];
#pragma unroll
      for (int nb = 0; nb < 4; nb++)
        o[rt][nb] = __builtin_amdgcn_mfma_f32_16x16x32_bf16(A.s8, Bv[nb].s8, o[rt][nb], 0, 0, 0);
    }
  }

  // ---- epilogue ----
  float lred[2][4];
#pragma unroll
  for (int rt = 0; rt < 2; rt++)
#pragma unroll
    for (int reg = 0; reg < 4; reg++) {
      float l = l_part[rt][reg];
#pragma unroll
      for (int m = 1; m <= 8; m <<= 1) l += __shfl_xor(l, m, 64);
      lred[rt][reg] = l;
    }
  if (lr == 0) {
#pragma unroll
    for (int rt = 0; rt < 2; rt++)
#pragma unroll
      for (int reg = 0; reg < 4; reg++)
        lExch[khalf * 64 + rowgrp * 32 + rt * 16 + quad * 4 + reg] = lred[rt][reg];
  }
  barrier_lds();

  float inv_l[2][4];
#pragma unroll
  for (int rt = 0; rt < 2; rt++)
#pragma unroll
    for (int reg = 0; reg < 4; reg++) {
      const int row = rowgrp * 32 + rt * 16 + quad * 4 + reg;
      inv_l[rt][reg] = 1.f / (lred[rt][reg] + lExch[(1 ^ khalf) * 64 + row]);
    }

  float s1p[2][4], s2p[2][4];
#pragma unroll
  for (int rt = 0; rt < 2; rt++)
#pragma unroll
    for (int reg = 0; reg < 4; reg++) {
      float s1 = 0.f, s2 = 0.f;
#pragma unroll
      for (int nb = 0; nb < 4; nb++) {
        float v = o[rt][nb][reg] * inv_l[rt][reg];
        o[rt][nb][reg] = v;
        s1 += v; s2 += v * v;
      }
#pragma unroll
      for (int m = 1; m <= 8; m <<= 1) {
        s1 += __shfl_xor(s1, m, 64);
        s2 += __shfl_xor(s2, m, 64);
      }
      s1p[rt][reg] = s1; s2p[rt][reg] = s2;
    }
  if (lr == 0) {
#pragma unroll
    for (int rt = 0; rt < 2; rt++)
#pragma unroll
      for (int reg = 0; reg < 4; reg++) {
        const int row = rowgrp * 32 + rt * 16 + quad * 4 + reg;
        sExch[(khalf * 64 + row) * 2 + 0] = s1p[rt][reg];
        sExch[(khalf * 64 + row) * 2 + 1] = s2p[rt][reg];
      }
  }
  barrier_lds();

  float gam[4], bet[4];
#pragma unroll
  for (int nb = 0; nb < 4; nb++) {
    gam[nb] = gammag[khalf * 64 + nb * 16 + lr];
    bet[nb] = betag[khalf * 64 + nb * 16 + lr];
  }

#pragma unroll
  for (int rt = 0; rt < 2; rt++)
#pragma unroll
    for (int reg = 0; reg < 4; reg++) {
      const int row = rowgrp * 32 + rt * 16 + quad * 4 + reg;
      const float s1 = s1p[rt][reg] + sExch[((1 ^ khalf) * 64 + row) * 2 + 0];
      const float s2 = s2p[rt][reg] + sExch[((1 ^ khalf) * 64 + row) * 2 + 1];
      const float mean = s1 * (1.f / 128.f);
      const float var  = s2 * (1.f / 128.f) - mean * mean;
      const float rstd = rsqrtf(var + LN_EPS);

      float* op = outg + ((size_t)b * LQ_ + q0 + row) * D_ + khalf * 64 + lr;
#pragma unroll
      for (int nb = 0; nb < 4; nb++)
        op[nb * 16] = (o[rt][nb][reg] - mean) * rstd * gam[nb] + bet[nb];
    }
}

extern "C" void kernel_launch(void* const* d_in, const int* in_sizes, int n_in,
                              void* d_out, int out_size, void* d_ws, size_t ws_size,
                              hipStream_t stream) {
  const float* q     = (const float*)d_in[0];
  const float* k     = (const float*)d_in[1];
  const float* v     = (const float*)d_in[2];
  const float* mask  = (const float*)d_in[3];
  const float* gamma = (const float*)d_in[4];
  const float* beta  = (const float*)d_in[5];
  float* out = (float*)d_out;

  attn_ln_mfma<<<dim3(512), dim3(256), 0, stream>>>(q, k, v, mask, gamma, beta, out);
}